// Round 5
// baseline (690.820 us; speedup 1.0000x reference)
//
#include <hip/hip_runtime.h>
#include <hip/hip_bf16.h>
#include <stdint.h>

// B=32, T=2048, E=D=A=1024. f32 I/O; x_lens int32.
// Output = [context (32*1024) ; att (32*2048)] f32.
// Pipeline (5 launches): fused prep (cvt enc->bf16 | W_encT bf16 | dec_proj)
// -> bf16-MFMA energy GEMM (BK=64, 2xBK32 LDS buffers, XCD swizzle,
// global_load_lds w=16) -> softmax -> context partials -> reduce.

typedef __bf16 bf16;
typedef __bf16 bf16x8 __attribute__((ext_vector_type(8)));
typedef float floatx4 __attribute__((ext_vector_type(4)));

#define T_DIM 2048
#define B_DIM 32
#define K_DIM 1024   // E
#define N_DIM 1024   // A
#define M_DIM (B_DIM * T_DIM)
#define ENC_ELEMS ((size_t)M_DIM * K_DIM)   // 64M

__device__ __forceinline__ void async_copy16(const bf16* g, bf16* l) {
    __builtin_amdgcn_global_load_lds(
        (const __attribute__((address_space(1))) void*)g,
        (__attribute__((address_space(3))) void*)l, 16, 0, 0);
}

__device__ __forceinline__ float fast_tanh(float x) {
    float ax = fabsf(x);
    float e  = __expf(ax + ax);
    float t  = 1.f - 2.f / (e + 1.f);
    return copysignf(t, x);
}

// ------------- fused prep: cvt enc | transpose W_enc | dec_proj -------------
// grid: [0,2048) cvt | [2048,2304) transpose | [2304,2432) decproj
__global__ __launch_bounds__(256) void prep_kernel(
        const float* __restrict__ enc, bf16* __restrict__ encb,
        const float* __restrict__ Wenc, bf16* __restrict__ WT,
        const float* __restrict__ dec, const float* __restrict__ Wdec,
        const float* __restrict__ benc, float* __restrict__ dproj,
        int do_cvt) {
    __shared__ bf16 tile[64][65];
    __shared__ float sdec[1024];
    const int bid = blockIdx.x, tid = threadIdx.x;

    if (bid < 2048) {                       // ---- cvt enc f32 -> bf16
        if (!do_cvt) return;
        size_t i = ((size_t)bid * 256 + tid) * 8;
        const size_t stride = (size_t)2048 * 256 * 8;
        for (; i < ENC_ELEMS; i += stride) {
            float4 f0 = *(const float4*)(enc + i);
            float4 f1 = *(const float4*)(enc + i + 4);
            bf16x8 w;
            w[0] = (bf16)f0.x; w[1] = (bf16)f0.y; w[2] = (bf16)f0.z; w[3] = (bf16)f0.w;
            w[4] = (bf16)f1.x; w[5] = (bf16)f1.y; w[6] = (bf16)f1.z; w[7] = (bf16)f1.w;
            *(bf16x8*)(encb + i) = w;
        }
    } else if (bid < 2304) {                // ---- W_enc [E,A] -> WT bf16 [A,E]
        const int idx = bid - 2048;
        const int e0 = (idx & 15) * 64, a0 = (idx >> 4) * 64;
        const int c = tid & 63, r0 = tid >> 6;
#pragma unroll
        for (int p = 0; p < 16; ++p) {
            int r = p * 4 + r0;
            tile[r][c] = (bf16)Wenc[(size_t)(e0 + r) * 1024 + a0 + c];
        }
        __syncthreads();
#pragma unroll
        for (int p = 0; p < 16; ++p) {
            int r = p * 4 + r0;
            WT[(size_t)(a0 + r) * 1024 + e0 + c] = tile[c][r];
        }
    } else {                                // ---- dec_proj
        const int idx = bid - 2304;
        const int b = idx >> 2;
        const int a = (idx & 3) * 256 + tid;
        for (int i = tid; i < 1024; i += 256) sdec[i] = dec[b * 1024 + i];
        __syncthreads();
        float acc = benc[a];
#pragma unroll 8
        for (int d = 0; d < 1024; ++d) acc += sdec[d] * Wdec[(size_t)d * 1024 + a];
        dproj[b * 1024 + a] = acc;
    }
}

// ------------- fused energy GEMM: BK=64 (two BK32 LDS buffers) --------------
__global__ __launch_bounds__(256) void energy_gemm_bf16(
        const bf16* __restrict__ encb, const bf16* __restrict__ WT,
        const float* __restrict__ dproj, const float* __restrict__ v,
        float* __restrict__ part) {
    __shared__ __align__(16) bf16 As[2][128 * 32];   // 16 KB
    __shared__ __align__(16) bf16 Bs[2][128 * 32];   // 16 KB
    __shared__ float esum[128];

    const int tid  = threadIdx.x;
    const int lane = tid & 63;
    const int wave = tid >> 6;
    const int wy = wave >> 1, wx = wave & 1;

    // XCD swizzle: all 8 n-chunks of one m-tile land on ONE XCD, consecutive.
    const int L = blockIdx.x;
    const int xcd  = L & 7;
    const int slot = L >> 3;
    const int m_tile = xcd * 64 + (slot >> 3);
    const int n_chunk = slot & 7;
    const int m0 = m_tile * 128;
    const int n0 = n_chunk * 128;
    const int b  = m0 >> 11;

    if (tid < 128) esum[tid] = 0.f;

    floatx4 acc[4][4];
#pragma unroll
    for (int i = 0; i < 4; ++i)
#pragma unroll
        for (int j = 0; j < 4; ++j) acc[i][j] = (floatx4){0.f, 0.f, 0.f, 0.f};

    // wave w stages rows [w*32, w*32+32): lane covers row w*32+(l>>2) (+16),
    // col chunk (l&3)*8 of the 32-wide K half. LDS dest = uniform base + 16*lane.
    const bf16* gA = encb + (size_t)(m0 + wave * 32 + (lane >> 2)) * 1024 + (lane & 3) * 8;
    const bf16* gB = WT   + (size_t)(n0 + wave * 32 + (lane >> 2)) * 1024 + (lane & 3) * 8;
    bf16* lA = As[0] + wave * 1024;    // As[1] = +4096 elems
    bf16* lB = Bs[0] + wave * 1024;

    for (int k0 = 0; k0 < K_DIM; k0 += 64) {
        __syncthreads();                      // prev MFMA reads done
        // half 0 (k0..k0+32)
        async_copy16(gA + k0, lA);
        async_copy16(gA + (size_t)16 * 1024 + k0, lA + 512);
        async_copy16(gB + k0, lB);
        async_copy16(gB + (size_t)16 * 1024 + k0, lB + 512);
        // half 1 (k0+32..k0+64)
        async_copy16(gA + k0 + 32, lA + 4096);
        async_copy16(gA + (size_t)16 * 1024 + k0 + 32, lA + 4096 + 512);
        async_copy16(gB + k0 + 32, lB + 4096);
        async_copy16(gB + (size_t)16 * 1024 + k0 + 32, lB + 4096 + 512);
        __syncthreads();                      // drains vmcnt -> LDS valid

#pragma unroll
        for (int h = 0; h < 2; ++h) {
            bf16x8 af[4], bfr[4];
#pragma unroll
            for (int i = 0; i < 4; ++i)
                af[i] = *(const bf16x8*)(As[h] + (wy * 64 + i * 16 + (lane & 15)) * 32 + (lane >> 4) * 8);
#pragma unroll
            for (int i = 0; i < 4; ++i)
                bfr[i] = *(const bf16x8*)(Bs[h] + (wx * 64 + i * 16 + (lane & 15)) * 32 + (lane >> 4) * 8);
#pragma unroll
            for (int mi = 0; mi < 4; ++mi)
#pragma unroll
                for (int ni = 0; ni < 4; ++ni)
                    acc[mi][ni] = __builtin_amdgcn_mfma_f32_16x16x32_bf16(
                        af[mi], bfr[ni], acc[mi][ni], 0, 0, 0);
        }
    }
    __syncthreads();

    float vv[4], dp[4];
#pragma unroll
    for (int ni = 0; ni < 4; ++ni) {
        int col = n0 + wx * 64 + ni * 16 + (lane & 15);
        vv[ni] = v[col];
        dp[ni] = dproj[b * 1024 + col];
    }
#pragma unroll
    for (int mi = 0; mi < 4; ++mi) {
#pragma unroll
        for (int r = 0; r < 4; ++r) {
            float s = 0.f;
#pragma unroll
            for (int ni = 0; ni < 4; ++ni)
                s += vv[ni] * fast_tanh(acc[mi][ni][r] + dp[ni]);
            s += __shfl_xor(s, 1);
            s += __shfl_xor(s, 2);
            s += __shfl_xor(s, 4);
            s += __shfl_xor(s, 8);
            if ((lane & 15) == 0) {
                int row = wy * 64 + mi * 16 + (lane >> 4) * 4 + r;
                atomicAdd(&esum[row], s);
            }
        }
    }
    __syncthreads();
    if (tid < 128) part[(size_t)n_chunk * M_DIM + m0 + tid] = esum[tid];
}

// ------------- fallback f32-staged GEMM (small ws) --------------------------
__global__ __launch_bounds__(256) void energy_gemm_f32(
        const float* __restrict__ enc, const bf16* __restrict__ WT,
        const float* __restrict__ dproj, const float* __restrict__ v,
        float* __restrict__ part) {
    __shared__ __align__(16) bf16 As[128 * 32];
    __shared__ __align__(16) bf16 Bs[128 * 32];
    __shared__ float esum[128];

    const int tid  = threadIdx.x;
    const int lane = tid & 63;
    const int wave = tid >> 6;
    const int wy = wave >> 1, wx = wave & 1;
    const int L = blockIdx.x;
    const int xcd  = L & 7;
    const int slot = L >> 3;
    const int m_tile = xcd * 64 + (slot >> 3);
    const int n_chunk = slot & 7;
    const int m0 = m_tile * 128;
    const int n0 = n_chunk * 128;
    const int b  = m0 >> 11;

    if (tid < 128) esum[tid] = 0.f;

    floatx4 acc[4][4];
#pragma unroll
    for (int i = 0; i < 4; ++i)
#pragma unroll
        for (int j = 0; j < 4; ++j) acc[i][j] = (floatx4){0.f, 0.f, 0.f, 0.f};

    const int sr = tid >> 2;
    const int sc = (tid & 3) * 8;
    const float* gA = enc + (size_t)(m0 + sr) * 1024 + sc;
    const bf16*  gB = WT  + (size_t)(n0 + sr) * 1024 + sc;
    bf16* lA = As + sr * 32 + sc;
    bf16* lB = Bs + sr * 32 + sc;

    for (int k0 = 0; k0 < K_DIM; k0 += 32) {
        __syncthreads();
#pragma unroll
        for (int rep = 0; rep < 2; ++rep) {
            const float4* p = (const float4*)(gA + (size_t)rep * 64 * 1024 + k0);
            float4 f0 = p[0], f1 = p[1];
            bf16x8 w;
            w[0] = (bf16)f0.x; w[1] = (bf16)f0.y; w[2] = (bf16)f0.z; w[3] = (bf16)f0.w;
            w[4] = (bf16)f1.x; w[5] = (bf16)f1.y; w[6] = (bf16)f1.z; w[7] = (bf16)f1.w;
            *(bf16x8*)(lA + rep * 64 * 32) = w;
            *(bf16x8*)(lB + rep * 64 * 32) =
                *(const bf16x8*)(gB + (size_t)rep * 64 * 1024 + k0);
        }
        __syncthreads();

        bf16x8 af[4], bfr[4];
#pragma unroll
        for (int i = 0; i < 4; ++i)
            af[i] = *(const bf16x8*)(As + (wy * 64 + i * 16 + (lane & 15)) * 32 + (lane >> 4) * 8);
#pragma unroll
        for (int i = 0; i < 4; ++i)
            bfr[i] = *(const bf16x8*)(Bs + (wx * 64 + i * 16 + (lane & 15)) * 32 + (lane >> 4) * 8);
#pragma unroll
        for (int mi = 0; mi < 4; ++mi)
#pragma unroll
            for (int ni = 0; ni < 4; ++ni)
                acc[mi][ni] = __builtin_amdgcn_mfma_f32_16x16x32_bf16(
                    af[mi], bfr[ni], acc[mi][ni], 0, 0, 0);
    }
    __syncthreads();

    float vv[4], dp[4];
#pragma unroll
    for (int ni = 0; ni < 4; ++ni) {
        int col = n0 + wx * 64 + ni * 16 + (lane & 15);
        vv[ni] = v[col];
        dp[ni] = dproj[b * 1024 + col];
    }
#pragma unroll
    for (int mi = 0; mi < 4; ++mi) {
#pragma unroll
        for (int r = 0; r < 4; ++r) {
            float s = 0.f;
#pragma unroll
            for (int ni = 0; ni < 4; ++ni)
                s += vv[ni] * fast_tanh(acc[mi][ni][r] + dp[ni]);
            s += __shfl_xor(s, 1);
            s += __shfl_xor(s, 2);
            s += __shfl_xor(s, 4);
            s += __shfl_xor(s, 8);
            if ((lane & 15) == 0) {
                int row = wy * 64 + mi * 16 + (lane >> 4) * 4 + r;
                atomicAdd(&esum[row], s);
            }
        }
    }
    __syncthreads();
    if (tid < 128) part[(size_t)n_chunk * M_DIM + m0 + tid] = esum[tid];
}

// ------------- masked softmax over T (multiplicative 0/1 mask) --------------
__global__ __launch_bounds__(256) void softmax_kernel(
        const float* __restrict__ part, const int* __restrict__ xlens,
        float* __restrict__ att) {
    const int b = blockIdx.x, tid = threadIdx.x;
    const int len = xlens[b];
    float e[8];
    float mx = -3.4e38f;
#pragma unroll
    for (int i = 0; i < 8; ++i) {
        const int t = tid + i * 256;
        float s = 0.f;
#pragma unroll
        for (int c = 0; c < 8; ++c) s += part[(size_t)c * M_DIM + b * 2048 + t];
        e[i] = (t < len) ? s : 0.f;
        mx = fmaxf(mx, e[i]);
    }
#pragma unroll
    for (int off = 1; off < 64; off <<= 1) mx = fmaxf(mx, __shfl_xor(mx, off));
    __shared__ float sr1[4], sr2[4];
    if ((tid & 63) == 0) sr1[tid >> 6] = mx;
    __syncthreads();
    mx = fmaxf(fmaxf(sr1[0], sr1[1]), fmaxf(sr1[2], sr1[3]));
    float sum = 0.f;
#pragma unroll
    for (int i = 0; i < 8; ++i) { e[i] = __expf(e[i] - mx); sum += e[i]; }
#pragma unroll
    for (int off = 1; off < 64; off <<= 1) sum += __shfl_xor(sum, off);
    if ((tid & 63) == 0) sr2[tid >> 6] = sum;
    __syncthreads();
    sum = sr2[0] + sr2[1] + sr2[2] + sr2[3];
    const float inv = 1.f / sum;
#pragma unroll
    for (int i = 0; i < 8; ++i)
        att[b * 2048 + tid + i * 256] = e[i] * inv;
}

// ------------- context partials: bf16x8 loads, t-split ----------------------
// thread group th=tid>>7 handles t in [th*64, th*64+64), cols (tid&127)*8..+8
__global__ __launch_bounds__(256) void context_part_kernel(
        const bf16* __restrict__ encb, const float* __restrict__ att,
        float* __restrict__ ctxpart) {
    const int b = blockIdx.x, chunk = blockIdx.y, tid = threadIdx.x;
    const int t0 = chunk * 128, th = tid >> 7, col = (tid & 127) * 8;
    __shared__ float satt[128];
    if (tid < 128) satt[tid] = att[b * 2048 + t0 + tid];
    __syncthreads();
    const bf16* base = encb + ((size_t)b * 2048 + t0 + th * 64) * 1024 + col;
    float a0 = 0.f, a1 = 0.f, a2 = 0.f, a3 = 0.f;
    float a4 = 0.f, a5 = 0.f, a6 = 0.f, a7 = 0.f;
#pragma unroll 4
    for (int t = 0; t < 64; ++t) {
        bf16x8 ev = *(const bf16x8*)(base + (size_t)t * 1024);
        float w = satt[th * 64 + t];
        a0 += w * (float)ev[0]; a1 += w * (float)ev[1];
        a2 += w * (float)ev[2]; a3 += w * (float)ev[3];
        a4 += w * (float)ev[4]; a5 += w * (float)ev[5];
        a6 += w * (float)ev[6]; a7 += w * (float)ev[7];
    }
    float* o = ctxpart + (((size_t)b * 16 + chunk) * 2 + th) * 1024 + col;
    *(float4*)(o)     = (float4){a0, a1, a2, a3};
    *(float4*)(o + 4) = (float4){a4, a5, a6, a7};
}

__global__ __launch_bounds__(256) void context_reduce_kernel(
        const float* __restrict__ ctxpart, float* __restrict__ out_ctx) {
    const int i = blockIdx.x * 256 + threadIdx.x;     // 0..32767
    const int b = i >> 10, e = i & 1023;
    const float* p = ctxpart + (size_t)b * 32 * 1024 + e;
    float s = 0.f;
#pragma unroll
    for (int c = 0; c < 32; ++c) s += p[c * 1024];
    out_ctx[i] = s;
}

// ------------- fallback context (f32 enc + atomics) -------------------------
__global__ __launch_bounds__(256) void context_kernel_f32(
        const float* __restrict__ enc, const float* __restrict__ att,
        float* __restrict__ ctx) {
    const int b = blockIdx.x, t0 = blockIdx.y * 128, tid = threadIdx.x;
    __shared__ float satt[128];
    if (tid < 128) satt[tid] = att[b * 2048 + t0 + tid];
    __syncthreads();
    const float* base = enc + ((size_t)b * 2048 + t0) * 1024 + tid * 4;
    float a0 = 0.f, a1 = 0.f, a2 = 0.f, a3 = 0.f;
    for (int t = 0; t < 128; ++t) {
        float4 ev = *(const float4*)(base + (size_t)t * 1024);
        float w = satt[t];
        a0 += w * ev.x; a1 += w * ev.y; a2 += w * ev.z; a3 += w * ev.w;
    }
    float* o = ctx + b * 1024 + tid * 4;
    atomicAdd(o + 0, a0); atomicAdd(o + 1, a1);
    atomicAdd(o + 2, a2); atomicAdd(o + 3, a3);
}

extern "C" void kernel_launch(void* const* d_in, const int* in_sizes, int n_in,
                              void* d_out, int out_size, void* d_ws, size_t ws_size,
                              hipStream_t stream) {
    const float* enc   = (const float*)d_in[0];
    const int*   xlens = (const int*)d_in[1];
    const float* dec   = (const float*)d_in[2];
    const float* Wenc  = (const float*)d_in[4];
    const float* benc  = (const float*)d_in[5];
    const float* Wdec  = (const float*)d_in[6];
    const float* v     = (const float*)d_in[7];

    float* out_ctx = (float*)d_out;
    float* out_att = out_ctx + B_DIM * K_DIM;

    char* ws = (char*)d_ws;
    float* dproj   = (float*)ws;                                  // 128 KB
    bf16*  WT      = (bf16*)(ws + (128u << 10));                  // 2 MB
    float* part    = (float*)(ws + (128u << 10) + (2u << 20));    // 2 MB
    bf16*  encb    = (bf16*)(ws + (128u << 10) + (4u << 20));     // 128 MB
    float* ctxpart = (float*)(ws + (128u << 10) + (4u << 20) + (ENC_ELEMS * 2)); // 4 MB
    const size_t need = (128u << 10) + (4u << 20) + ENC_ELEMS * 2 + (4u << 20);

    if (ws_size >= need) {
        prep_kernel<<<2432, 256, 0, stream>>>(enc, encb, Wenc, WT, dec, Wdec,
                                              benc, dproj, 1);
        energy_gemm_bf16<<<4096, 256, 0, stream>>>(encb, WT, dproj, v, part);
        softmax_kernel<<<B_DIM, 256, 0, stream>>>(part, xlens, out_att);
        context_part_kernel<<<dim3(B_DIM, 16), 256, 0, stream>>>(encb, out_att, ctxpart);
        context_reduce_kernel<<<B_DIM * K_DIM / 256, 256, 0, stream>>>(ctxpart, out_ctx);
    } else {
        hipMemsetAsync(out_ctx, 0, B_DIM * K_DIM * sizeof(float), stream);
        prep_kernel<<<2432, 256, 0, stream>>>(enc, (bf16*)nullptr, Wenc, WT,
                                              dec, Wdec, benc, dproj, 0);
        energy_gemm_f32<<<4096, 256, 0, stream>>>(enc, WT, dproj, v, part);
        softmax_kernel<<<B_DIM, 256, 0, stream>>>(part, xlens, out_att);
        context_kernel_f32<<<dim3(B_DIM, 16), 256, 0, stream>>>(enc, out_att, out_ctx);
    }
}